// Round 10
// baseline (708.182 us; speedup 1.0000x reference)
//
#include <hip/hip_runtime.h>
#include <math.h>

#define N 96
#define PAD 100        // padded LDS row stride (floats); 400 B = 25 float4s
#define T 768          // 12 waves, one workgroup, one CU
#define ITERS 50
#define LW 52          // neighbor-list width (u16 entries, padded to x4)

typedef float f2 __attribute__((ext_vector_type(2)));
typedef float f4 __attribute__((ext_vector_type(4)));
typedef unsigned short u16x4 __attribute__((ext_vector_type(4)));

// lane-group max via DPP (VALU pipe, no LDS traffic); CTRL must be constexpr
template <int CTRL>
__device__ __forceinline__ float dppmax(float m) {
    int mi = __builtin_bit_cast(int, m);
    int sw = __builtin_amdgcn_update_dpp(mi, mi, CTRL, 0xf, 0xf, true);
    return fmaxf(m, __builtin_bit_cast(float, sw));
}
#define DPP_XOR1 0xB1  // quad_perm:[1,0,3,2]
#define DPP_XOR2 0x4E  // quad_perm:[2,3,0,1]
#define DPP_SHL4 0x104 // row_shl:4  (dest l <- src l+4; OOB -> 0, safe: data >= 0)

// Fully fused MPM, one workgroup, 3 barriers/iter.
// M-phase: t = g*192 + cg*8 + q : g=row group (j≡g mod 4, 24 rows),
//          cg=col quad (cols 4cg..4cg+3), q=b-eighth (b in [12q,12q+12)).
//          W[4][12] as f2 pairs (48 VGPRs); packed muls + v_max3; 8-lane
//          combine = DPP xor1,xor2,row_shl4; q==0 writes float4 to Ms.
// Agg:     cq=t%24 -> cols 4cq..4cq+3 ; rows i = t/24 + 32k (k=0..2);
//          float4 neighbor gathers via float4-index lists; diag X in regs.
__global__ __launch_bounds__(T, 1) void k_fused(const float* __restrict__ A,
                                                const float* __restrict__ vec,
                                                float* __restrict__ out) {
    __shared__ float Xs[N * PAD];            // 38400 B : X (staging B, then A)
    __shared__ float Ms[(N + 1) * PAD];      // 38800 B : full M + zero row 96
    __shared__ unsigned short lst[N * LW];   //  9984 B : nbr float4-indices (j*25)
    __shared__ short cnt4[N];                // padded counts (multiple of 4)
    __shared__ float degA[N];
    __shared__ float degB[N];
    __shared__ float red[T / 64];

    const int t = threadIdx.x;
    const int g = t / 192;                 // M row group 0..3 (wave-uniform)
    const int r = t % 192;
    const int cg = r >> 3;                 // M col quad 0..23
    const int q = r & 7;                   // b-eighth
    const int cq = t % 24;                 // agg col quad
    const int rw = t / 24;                 // agg row slot 0..31
    const float s1 = 1.0f / (1.0f + expf(-1.0f));   // sigmoid(1) = diag of B
    const float s1s1 = s1 * s1;

    // ---- setup phase 0: B -> Xs (staging) ----
#pragma unroll
    for (int k = 0; k < 12; ++k) {
        int e = t + k * T;
        int rr = e / N, cc = e % N;
        float logit;
        if (rr == cc) {
            logit = 1.0f;
        } else {
            int i = rr < cc ? rr : cc;
            int j = rr < cc ? cc : rr;
            int idx = i * 95 - (i * (i - 1)) / 2 + (j - i - 1);
            logit = vec[idx];
        }
        Xs[rr * PAD + cc] = 1.0f / (1.0f + expf(-logit));
    }
    __syncthreads();

    // W tiles as f2 pairs (B symmetric: col a == row a), diag = 0
    f2 Wp[4][6];
#pragma unroll
    for (int c = 0; c < 4; ++c) {
        int ac = 4 * cg + c;
#pragma unroll
        for (int bp = 0; bp < 6; ++bp) {
            int b = 12 * q + 2 * bp;
            float w0 = (b == ac) ? 0.f : Xs[b * PAD + ac] * s1s1;
            float w1 = (b + 1 == ac) ? 0.f : Xs[(b + 1) * PAD + ac] * s1s1;
            Wp[c][bp] = (f2){w0, w1};
        }
    }

    if (t < N) {
        float s = 0.f;
        for (int rr = 0; rr < N; ++rr) s += Xs[rr * PAD + t];
        degB[t] = s;
    }
    __syncthreads();   // all reads of B done

    // ---- setup phase 1: A -> Xs (staging) ----
#pragma unroll
    for (int k = 0; k < 12; ++k) {
        int e = t + k * T;
        Xs[(e / N) * PAD + (e % N)] = A[e];
    }
    __syncthreads();

    if (t < N) {
        float s = 0.f;
        for (int rr = 0; rr < N; ++rr) s += Xs[rr * PAD + t];   // A symmetric
        degA[t] = s;
    } else if (t < 2 * N) {
        int i = t - N;
        int c_ = 0;
        for (int j = 0; j < N; ++j) {
            if (j != i && Xs[j * PAD + i] > 0.5f)                // A symmetric
                lst[i * LW + c_++] = (unsigned short)(j * 25);   // float4 index
        }
        while (c_ & 3) lst[i * LW + c_++] = (unsigned short)(N * 25); // zero row
        cnt4[i] = (short)c_;
    }
    // zero row 96 of Ms (pad target) — written once, never overwritten
    if (t < PAD) Ms[N * PAD + t] = 0.0f;
    __syncthreads();   // lists/degs ready, Xs(A) reads done

    // node-sim coefficients + register-resident diag X (agg: 3 rows x 4 cols)
    f4 ns4[3], x4[3];
#pragma unroll
    for (int k = 0; k < 3; ++k) {
        int i = rw + 32 * k;
        ns4[k] = (f4){s1 / (fabsf(degA[i] - degB[4 * cq + 0]) + 1.0f),
                      s1 / (fabsf(degA[i] - degB[4 * cq + 1]) + 1.0f),
                      s1 / (fabsf(degA[i] - degB[4 * cq + 2]) + 1.0f),
                      s1 / (fabsf(degA[i] - degB[4 * cq + 3]) + 1.0f)};
        x4[k] = (f4)(1.0f / 96.0f);
    }

    // X0 = 1/96 everywhere (||X0|| = 1 exactly)
#pragma unroll
    for (int k = 0; k < 12; ++k) {
        int e = t + k * T;
        Xs[(e / N) * PAD + (e % N)] = (1.0f / 96.0f);
    }
    __syncthreads();

    const float* xbase = &Xs[g * PAD + 12 * q];   // row jj -> + jj*4*PAD
    const f4* Ms4 = (const f4*)Ms + cq;           // agg col-quad base

    // ---- main loop ----
    for (int it = 0; it < ITERS; ++it) {
        // M-phase: 24 rows j = 4*jj + g, 3 const-offset b128 reads per row
#pragma unroll 6
        for (int jj = 0; jj < 24; ++jj) {
            const float* xr = xbase + jj * 4 * PAD;
            f4 X0 = *(const f4*)(xr);
            f4 X1 = *(const f4*)(xr + 4);
            f4 X2 = *(const f4*)(xr + 8);
            f2 xp[6];
            xp[0] = (f2){X0.x, X0.y}; xp[1] = (f2){X0.z, X0.w};
            xp[2] = (f2){X1.x, X1.y}; xp[3] = (f2){X1.z, X1.w};
            xp[4] = (f2){X2.x, X2.y}; xp[5] = (f2){X2.z, X2.w};
            float m0 = 0.f, m1 = 0.f, m2 = 0.f, m3 = 0.f;
#pragma unroll
            for (int bp = 0; bp < 6; ++bp) {
                f2 p0 = Wp[0][bp] * xp[bp];              // v_pk_mul_f32
                f2 p1 = Wp[1][bp] * xp[bp];
                f2 p2 = Wp[2][bp] * xp[bp];
                f2 p3 = Wp[3][bp] * xp[bp];
                m0 = fmaxf(fmaxf(m0, p0.x), p0.y);       // v_max3_f32
                m1 = fmaxf(fmaxf(m1, p1.x), p1.y);
                m2 = fmaxf(fmaxf(m2, p2.x), p2.y);
                m3 = fmaxf(fmaxf(m3, p3.x), p3.y);
            }
            // exact 8-lane max combine, all on the VALU pipe
            m0 = dppmax<DPP_XOR1>(m0); m0 = dppmax<DPP_XOR2>(m0); m0 = dppmax<DPP_SHL4>(m0);
            m1 = dppmax<DPP_XOR1>(m1); m1 = dppmax<DPP_XOR2>(m1); m1 = dppmax<DPP_SHL4>(m1);
            m2 = dppmax<DPP_XOR1>(m2); m2 = dppmax<DPP_XOR2>(m2); m2 = dppmax<DPP_SHL4>(m2);
            m3 = dppmax<DPP_XOR1>(m3); m3 = dppmax<DPP_XOR2>(m3); m3 = dppmax<DPP_SHL4>(m3);
            if (q == 0)
                *(f4*)&Ms[(4 * jj + g) * PAD + 4 * cg] = (f4){m0, m1, m2, m3};
        }
        __syncthreads();   // (A) Ms complete; all Xs reads done

        // aggregate (diag from regs, then ascending-j neighbors — exact order)
        f4 y4[3];
#pragma unroll
        for (int k = 0; k < 3; ++k) {
            int i = rw + 32 * k;
            f4 acc = x4[k] * ns4[k];
            int nch = (int)cnt4[i] >> 2;
            const unsigned short* lp = &lst[i * LW];
            for (int cc = 0; cc < nch; ++cc) {
                u16x4 o = *(const u16x4*)(lp + 4 * cc);
                acc += Ms4[o.x];
                acc += Ms4[o.y];
                acc += Ms4[o.z];
                acc += Ms4[o.w];
            }
            y4[k] = acc;
        }

        // block-wide norm (deterministic fixed tree)
        float ss = 0.f;
#pragma unroll
        for (int k = 0; k < 3; ++k) {
            ss = fmaf(y4[k].x, y4[k].x, ss);
            ss = fmaf(y4[k].y, y4[k].y, ss);
            ss = fmaf(y4[k].z, y4[k].z, ss);
            ss = fmaf(y4[k].w, y4[k].w, ss);
        }
#pragma unroll
        for (int mm = 1; mm < 64; mm <<= 1) ss += __shfl_xor(ss, mm, 64);
        if ((t & 63) == 0) red[t >> 6] = ss;
        __syncthreads();   // (B) red ready; all Ms reads done
        float s = 0.f;
#pragma unroll
        for (int w2 = 0; w2 < T / 64; ++w2) s += red[w2];
        float inv = 1.0f / sqrtf(s);
#pragma unroll
        for (int k = 0; k < 3; ++k) {
            int i = rw + 32 * k;
            f4 xn = y4[k] * inv;
            x4[k] = xn;
            *(f4*)&Xs[i * PAD + 4 * cq] = xn;
        }
        __syncthreads();   // (C) Xs ready for next iter; Ms safe to overwrite
    }

    // ---- output ----
#pragma unroll
    for (int k = 0; k < 12; ++k) {
        int e = t + k * T;
        out[e] = Xs[(e / N) * PAD + (e % N)];
    }
}

extern "C" void kernel_launch(void* const* d_in, const int* in_sizes, int n_in,
                              void* d_out, int out_size, void* d_ws, size_t ws_size,
                              hipStream_t stream) {
    const float* A = (const float*)d_in[0];     // A_gt, 96*96
    const float* vec = (const float*)d_in[1];   // vec_logits, 4560
    float* out = (float*)d_out;
    k_fused<<<1, T, 0, stream>>>(A, vec, out);
}